// Round 14
// baseline (148.042 us; speedup 1.0000x reference)
//
#include <hip/hip_runtime.h>
#include <hip/hip_bf16.h>

typedef __attribute__((ext_vector_type(8))) short short8;
typedef __attribute__((ext_vector_type(4))) float f32x4;
typedef __attribute__((ext_vector_type(16))) float f32x16;

#define D_   1024
#define SEQ_ 2048
#define NB_  2
#define NH_  16
#define HD_  64
#define LDV_ 4096   // V^T row stride (= B*S)

using u16 = unsigned short;
using u32 = unsigned int;

static __device__ __forceinline__ u16 f2bf(float f) {
    union { __bf16 h; u16 u; } cv;
    cv.h = (__bf16)f;
    return cv.u;
}
static __device__ __forceinline__ float bf2f(u16 u) {
    union { unsigned int i; float f; } v;
    v.i = ((unsigned int)u) << 16;
    return v.f;
}
// pack two f32 -> dword of 2 bf16 (lo = a, hi = b)
static __device__ __forceinline__ u32 pkbf(float a, float b) {
    u32 r;
    asm volatile("v_cvt_pk_bf16_f32 %0, %1, %2" : "=v"(r) : "v"(a), "v"(b));
    return r;
}

// async global->LDS, 16B per lane
static __device__ __forceinline__ void glds16(const u16* g, u16* l) {
    __builtin_amdgcn_global_load_lds(
        (const __attribute__((address_space(1))) unsigned int*)g,
        (__attribute__((address_space(3))) unsigned int*)l, 16, 0, 0);
}

// ---------------- fused f32 -> bf16 convert (one launch for all 5 tensors) ----------------
__global__ __launch_bounds__(256)
void cvt_all(const float* __restrict__ x,  const float* __restrict__ wq,
             const float* __restrict__ wk, const float* __restrict__ wv,
             const float* __restrict__ wo,
             u16* __restrict__ xb,  u16* __restrict__ wqb, u16* __restrict__ wkb,
             u16* __restrict__ wvb, u16* __restrict__ wob)
{
    const int bid = blockIdx.x;
    const float* src; u16* dst; int off;
    if (bid < 2048)      { src = x;  dst = xb;  off = bid; }
    else if (bid < 2560) { src = wq; dst = wqb; off = bid - 2048; }
    else if (bid < 3072) { src = wk; dst = wkb; off = bid - 2560; }
    else if (bid < 3584) { src = wv; dst = wvb; off = bid - 3072; }
    else                 { src = wo; dst = wob; off = bid - 3584; }
    size_t i = ((size_t)off * 256 + threadIdx.x) * 8;
    float4 a = *(const float4*)&src[i];
    float4 b = *(const float4*)&src[i + 4];
    short8 o;
    o[0] = (short)f2bf(a.x); o[1] = (short)f2bf(a.y);
    o[2] = (short)f2bf(a.z); o[3] = (short)f2bf(a.w);
    o[4] = (short)f2bf(b.x); o[5] = (short)f2bf(b.y);
    o[6] = (short)f2bf(b.z); o[7] = (short)f2bf(b.w);
    *(short8*)&dst[i] = o;
}

// ---------------- bf16 GEMM core: Y[m][n] = sum_k A[m][k] * W[n][k] ----------------
// 128x128 tile, BK=32, global_load_lds staging, double-buffered linear LDS (m97 pattern).
template<int OUT_F32>
static __device__ __forceinline__
void gemm_core(const u16* __restrict__ A, const u16* __restrict__ W,
               void* __restrict__ Y, int ldY, int mBase, int nBase,
               u16* lA, u16* lB)
{
    const int t    = threadIdx.x;
    const int lane = t & 63, wid = t >> 6;
    const int wr = wid >> 1, wc = wid & 1;
    const int lr = lane & 15, lg = lane >> 4;

    f32x4 acc[4][4] = {};

    const int srow = t >> 2;         // staging row (+64 for j=1)
    const int scol = (t & 3) * 8;    // staging col (u16)
    const u16* Ag = A + (size_t)(mBase + srow) * D_ + scol;
    const u16* Wg = W + (size_t)(nBase + srow) * D_ + scol;
    const int ldsoff = t * 8;

    auto stage = [&](int buf, int kt) {
#pragma unroll
        for (int j = 0; j < 2; ++j) {
            glds16(Ag + (size_t)j * 64 * D_ + kt * 32, lA + buf * 4096 + j * 2048 + ldsoff);
            glds16(Wg + (size_t)j * 64 * D_ + kt * 32, lB + buf * 4096 + j * 2048 + ldsoff);
        }
    };

    stage(0, 0);
    asm volatile("s_waitcnt vmcnt(0)" ::: "memory");
    __syncthreads();

    int cur = 0;
    for (int kt = 0; kt < 32; ++kt) {
        if (kt < 31) stage(cur ^ 1, kt + 1);
        short8 af[4], bfv[4];
#pragma unroll
        for (int m = 0; m < 4; ++m)
            af[m] = *(const short8*)&lA[cur * 4096 + (wr * 64 + m * 16 + lr) * 32 + lg * 8];
#pragma unroll
        for (int n = 0; n < 4; ++n)
            bfv[n] = *(const short8*)&lB[cur * 4096 + (wc * 64 + n * 16 + lr) * 32 + lg * 8];
        __builtin_amdgcn_s_setprio(1);
#pragma unroll
        for (int m = 0; m < 4; ++m)
#pragma unroll
            for (int n = 0; n < 4; ++n)
                acc[m][n] = __builtin_amdgcn_mfma_f32_16x16x32_bf16(af[m], bfv[n], acc[m][n], 0, 0, 0);
        __builtin_amdgcn_s_setprio(0);
        if (kt < 31) {
            asm volatile("s_waitcnt vmcnt(0)" ::: "memory");
            __syncthreads();
        }
        cur ^= 1;
    }

#pragma unroll
    for (int m = 0; m < 4; ++m)
#pragma unroll
        for (int n = 0; n < 4; ++n)
#pragma unroll
            for (int r = 0; r < 4; ++r) {
                int row = mBase + wr * 64 + m * 16 + lg * 4 + r;
                int col = nBase + wc * 64 + n * 16 + lr;
                if (OUT_F32)
                    ((float*)Y)[(size_t)row * ldY + col] = acc[m][n][r];
                else
                    ((u16*)Y)[(size_t)row * ldY + col] = f2bf(acc[m][n][r]);
            }
}

// fused QKV: z=0 -> Q = x Wq^T, z=1 -> K = x Wk^T, z=2 -> V^T = Wv x^T
__global__ __launch_bounds__(256)
void gemm_qkv(const u16* __restrict__ xb, const u16* __restrict__ wq, const u16* __restrict__ wk,
              const u16* __restrict__ wv, u16* __restrict__ Qo, u16* __restrict__ Ko,
              u16* __restrict__ Vto)
{
    __shared__ u16 lA[2 * 128 * 32];
    __shared__ u16 lB[2 * 128 * 32];
    const int z = blockIdx.z;
    if (z == 0)
        gemm_core<0>(xb, wq, Qo, D_, blockIdx.x * 128, blockIdx.y * 128, lA, lB);
    else if (z == 1)
        gemm_core<0>(xb, wk, Ko, D_, blockIdx.x * 128, blockIdx.y * 128, lA, lB);
    else
        gemm_core<0>(wv, xb, Vto, LDV_, blockIdx.y * 128, blockIdx.x * 128, lA, lB);
}

__global__ __launch_bounds__(256)
void gemm_out(const u16* __restrict__ Ab, const u16* __restrict__ wo, float* __restrict__ out)
{
    __shared__ u16 lA[2 * 128 * 32];
    __shared__ u16 lB[2 * 128 * 32];
    gemm_core<1>(Ab, wo, out, D_, blockIdx.x * 128, blockIdx.y * 128, lA, lB);
}

// ---------------- causal flash attention (round-14: r12 core widened to 128-key pairs) ----------------
// Proven r12 per-wave structure (zero-LDS, zero-barrier, in-register swapped softmax,
// cvt_pk+permlane PA build), but each iteration processes TWO 64-key sub-tiles (A at kb,
// B at kb+64): one softmax pass over 64 in-register scores (trees+2 shfls amortized 2x),
// two independent QK/PV MFMA chains (2x ILP). Iterations 33.8K -> 17.4K total.
// Causal mask applied to BOTH sub-tiles on the last pair only (covers B-beyond-end:
// keys > qrow are exactly the invalid ones). K prefetch reuses kfA/kfB registers in-place;
// vfB loaded after softmax to cap live VGPRs (~230 <= 256 -> 2 waves/SIMD, no spill).
// 1024 blocks x 2 waves: wave0 -> q-group 63-px, wave1 -> px (r12 mapping, proven).
__global__ __launch_bounds__(128)
void attn_fwd(const u16* __restrict__ Q, const u16* __restrict__ K,
              const u16* __restrict__ Vt, u16* __restrict__ O)
{
    const int l   = threadIdx.x & 63;   // lane within wave
    const int wid = threadIdx.x >> 6;   // 0 or 1
    const int lq = l & 31;              // q-col within tile / hd-col
    const int hk = l >> 5;              // k-half selector (0/1)
    const int id = (int)blockIdx.x;
    const int bh = id & 31;             // id%8 -> XCD-local K/V
    const int px = id >> 5;             // 0..31
    const int b = bh >> 4, h = bh & 15;

    const u16* Qb = Q  + (size_t)b * SEQ_ * D_ + h * HD_;
    const u16* Kb = K  + (size_t)b * SEQ_ * D_ + h * HD_;
    const u16* Vg = Vt + (size_t)(h * HD_) * LDV_ + (size_t)b * SEQ_;
    u16*       Ob = O  + (size_t)b * SEQ_ * D_ + h * HD_;

    const int g     = wid ? px : (63 - px);   // this wave's 32-row q-group
    const int qbase = g * 32;
    const int qrow  = qbase + lq;
    const int ptmax = g >> 2;                 // last 128-key pair index

    // Q fragments (B-operand): qf[c][i] = Q[qrow][16c + 8hk + i], scaled by 0.125*log2(e)
    short8 qf[4];
#pragma unroll
    for (int c = 0; c < 4; ++c) {
        short8 v = *(const short8*)&Qb[(size_t)qrow * D_ + c * 16 + hk * 8];
#pragma unroll
        for (int i = 0; i < 8; ++i)
            v[i] = (short)f2bf(bf2f((u16)v[i]) * 0.18033688011112042f);
        qf[c] = v;
    }

    f32x16 accO[2] = {};        // O[q][hd]: col=hd=32t+lq, row=q=(r&3)+8(r>>2)+4hk
    float m_r = -1e30f, l_r = 0.f;

    // K fragments for tiles 0 and 1 (rows 0..127 always in-bounds)
    short8 kfA[2][4], kfB[2][4];
#pragma unroll
    for (int t = 0; t < 2; ++t)
#pragma unroll
        for (int c = 0; c < 4; ++c) {
            kfA[t][c] = *(const short8*)&Kb[(size_t)(t * 32 + lq) * D_ + c * 16 + hk * 8];
            kfB[t][c] = *(const short8*)&Kb[(size_t)(64 + t * 32 + lq) * D_ + c * 16 + hk * 8];
        }

    for (int p = 0; p <= ptmax; ++p) {
        const int kb = p * 128;

        // V for sub-tile A (keys kb..kb+63): from V^T, L2; used ~500cy later at PV-A
        short8 vfA[2][4];
#pragma unroll
        for (int t = 0; t < 2; ++t)
#pragma unroll
            for (int c = 0; c < 4; ++c)
                vfA[t][c] = *(const short8*)&Vg[(size_t)(t * 32 + lq) * LDV_ + kb + c * 16 + hk * 8];

        // QK^T for both sub-tiles (independent MFMA chains)
        f32x16 stA[2] = {}, stB[2] = {};
        __builtin_amdgcn_s_setprio(1);
#pragma unroll
        for (int t = 0; t < 2; ++t)
#pragma unroll
            for (int c = 0; c < 4; ++c) {
                stA[t] = __builtin_amdgcn_mfma_f32_32x32x16_bf16(kfA[t][c], qf[c], stA[t], 0, 0, 0);
                stB[t] = __builtin_amdgcn_mfma_f32_32x32x16_bf16(kfB[t][c], qf[c], stB[t], 0, 0, 0);
            }
        __builtin_amdgcn_s_setprio(0);

        // prefetch next pair's K tiles (in-place register reuse; lands during softmax+PV)
        if (p < ptmax) {
#pragma unroll
            for (int t = 0; t < 2; ++t)
#pragma unroll
                for (int c = 0; c < 4; ++c) {
                    kfA[t][c] = *(const short8*)&Kb[(size_t)(kb + 128 + t * 32 + lq) * D_ + c * 16 + hk * 8];
                    kfB[t][c] = *(const short8*)&Kb[(size_t)(kb + 192 + t * 32 + lq) * D_ + c * 16 + hk * 8];
                }
        }

        // causal mask on the last pair: both sub-tiles (B may be entirely beyond the end;
        // key > qrow is exactly the invalid condition in all cases)
        if (p == ptmax) {
#pragma unroll
            for (int t = 0; t < 2; ++t)
#pragma unroll
                for (int r = 0; r < 16; ++r) {
                    const int crow = (r & 3) + 8 * (r >> 2) + 4 * hk;
                    if (kb + t * 32 + crow > qrow)      stA[t][r] = -1e30f;
                    if (kb + 64 + t * 32 + crow > qrow) stB[t][r] = -1e30f;
                }
        }

        // one softmax pass over all 64 in-register scores (exp2 domain);
        // partner lane^32 holds the other half of each row
        float m0 = fmaxf(stA[0][0], stA[0][1]), m1 = fmaxf(stA[0][2], stA[0][3]);
        float m2 = fmaxf(stA[1][0], stA[1][1]), m3 = fmaxf(stA[1][2], stA[1][3]);
#pragma unroll
        for (int r = 4; r < 16; r += 4) {
            m0 = fmaxf(m0, fmaxf(stA[0][r], stA[0][r + 1]));
            m1 = fmaxf(m1, fmaxf(stA[0][r + 2], stA[0][r + 3]));
            m2 = fmaxf(m2, fmaxf(stA[1][r], stA[1][r + 1]));
            m3 = fmaxf(m3, fmaxf(stA[1][r + 2], stA[1][r + 3]));
        }
#pragma unroll
        for (int r = 0; r < 16; r += 4) {
            m0 = fmaxf(m0, fmaxf(stB[0][r], stB[0][r + 1]));
            m1 = fmaxf(m1, fmaxf(stB[0][r + 2], stB[0][r + 3]));
            m2 = fmaxf(m2, fmaxf(stB[1][r], stB[1][r + 1]));
            m3 = fmaxf(m3, fmaxf(stB[1][r + 2], stB[1][r + 3]));
        }
        float pmax = fmaxf(fmaxf(m0, m1), fmaxf(m2, m3));
        pmax = fmaxf(pmax, __shfl_xor(pmax, 32));
        // defer-max (T13, THR=8)
        if (!__all(pmax <= m_r + 8.f)) {
            const float mn = fmaxf(m_r, pmax);
            const float al = exp2f(m_r - mn);
            m_r = mn;
            l_r *= al;
#pragma unroll
            for (int t = 0; t < 2; ++t)
#pragma unroll
                for (int r = 0; r < 16; ++r) accO[t][r] *= al;
        }
        float rs0 = 0.f, rs1 = 0.f, rs2 = 0.f, rs3 = 0.f;
#pragma unroll
        for (int t = 0; t < 2; ++t)
#pragma unroll
            for (int r = 0; r < 16; r += 4) {
                float p0 = exp2f(stA[t][r]     - m_r);
                float p1 = exp2f(stA[t][r + 1] - m_r);
                float p2 = exp2f(stA[t][r + 2] - m_r);
                float p3 = exp2f(stA[t][r + 3] - m_r);
                stA[t][r] = p0; stA[t][r + 1] = p1; stA[t][r + 2] = p2; stA[t][r + 3] = p3;
                rs0 += p0; rs1 += p1; rs2 += p2; rs3 += p3;
            }
#pragma unroll
        for (int t = 0; t < 2; ++t)
#pragma unroll
            for (int r = 0; r < 16; r += 4) {
                float p0 = exp2f(stB[t][r]     - m_r);
                float p1 = exp2f(stB[t][r + 1] - m_r);
                float p2 = exp2f(stB[t][r + 2] - m_r);
                float p3 = exp2f(stB[t][r + 3] - m_r);
                stB[t][r] = p0; stB[t][r + 1] = p1; stB[t][r + 2] = p2; stB[t][r + 3] = p3;
                rs0 += p0; rs1 += p1; rs2 += p2; rs3 += p3;
            }
        float rsum = (rs0 + rs1) + (rs2 + rs3);
        rsum += __shfl_xor(rsum, 32);
        l_r += rsum;

        // V for sub-tile B (keys kb+64..kb+127): issued here, used ~200cy later at PV-B
        short8 vfB[2][4];
#pragma unroll
        for (int t = 0; t < 2; ++t)
#pragma unroll
            for (int c = 0; c < 4; ++c)
                vfB[t][c] = *(const short8*)&Vg[(size_t)(t * 32 + lq) * LDV_ + kb + 64 + c * 16 + hk * 8];

        // PA build (T12) + PV for sub-tile A
        short8 pa[4];
#pragma unroll
        for (int c = 0; c < 4; ++c) {
            const int tt = c >> 1, base = (c & 1) * 8;
            u32 a0 = pkbf(stA[tt][base + 0], stA[tt][base + 1]);
            u32 b0 = pkbf(stA[tt][base + 4], stA[tt][base + 5]);
            u32 a1 = pkbf(stA[tt][base + 2], stA[tt][base + 3]);
            u32 b1 = pkbf(stA[tt][base + 6], stA[tt][base + 7]);
            asm volatile("v_permlane32_swap_b32 %0, %1" : "+v"(a0), "+v"(b0));
            asm volatile("v_permlane32_swap_b32 %0, %1" : "+v"(a1), "+v"(b1));
            union { u32 w[4]; short8 s; } u;
            u.w[0] = a0; u.w[1] = a1; u.w[2] = b0; u.w[3] = b1;
            pa[c] = u.s;
        }
        __builtin_amdgcn_s_setprio(1);
#pragma unroll
        for (int t = 0; t < 2; ++t)
#pragma unroll
            for (int c = 0; c < 4; ++c)
                accO[t] = __builtin_amdgcn_mfma_f32_32x32x16_bf16(pa[c], vfA[t][c], accO[t], 0, 0, 0);
        __builtin_amdgcn_s_setprio(0);

        // PA build + PV for sub-tile B
#pragma unroll
        for (int c = 0; c < 4; ++c) {
            const int tt = c >> 1, base = (c & 1) * 8;
            u32 a0 = pkbf(stB[tt][base + 0], stB[tt][base + 1]);
            u32 b0 = pkbf(stB[tt][base + 4], stB[tt][base + 5]);
            u32 a1 = pkbf(stB[tt][base + 2], stB[tt][base + 3]);
            u32 b1 = pkbf(stB[tt][base + 6], stB[tt][base + 7]);
            asm volatile("v_permlane32_swap_b32 %0, %1" : "+v"(a0), "+v"(b0));
            asm volatile("v_permlane32_swap_b32 %0, %1" : "+v"(a1), "+v"(b1));
            union { u32 w[4]; short8 s; } u;
            u.w[0] = a0; u.w[1] = a1; u.w[2] = b0; u.w[3] = b1;
            pa[c] = u.s;
        }
        __builtin_amdgcn_s_setprio(1);
#pragma unroll
        for (int t = 0; t < 2; ++t)
#pragma unroll
            for (int c = 0; c < 4; ++c)
                accO[t] = __builtin_amdgcn_mfma_f32_32x32x16_bf16(pa[c], vfB[t][c], accO[t], 0, 0, 0);
        __builtin_amdgcn_s_setprio(0);
    }

    // epilogue: O[q][hd] = accO / l; l_r lives at lane (q&31) -> gather via shfl
    const float inv = 1.f / l_r;
#pragma unroll
    for (int r = 0; r < 16; ++r) {
        const int qe = (r & 3) + 8 * (r >> 2) + 4 * hk;   // 0..31
        const float li = __shfl(inv, qe);
        const size_t qoff = (size_t)(qbase + qe) * D_;
#pragma unroll
        for (int t = 0; t < 2; ++t)
            Ob[qoff + t * 32 + lq] = f2bf(accO[t][r] * li);
    }
}

extern "C" void kernel_launch(void* const* d_in, const int* in_sizes, int n_in,
                              void* d_out, int out_size, void* d_ws, size_t ws_size,
                              hipStream_t stream)
{
    const float* x  = (const float*)d_in[0];
    const float* Wq = (const float*)d_in[1];
    const float* Wk = (const float*)d_in[2];
    const float* Wv = (const float*)d_in[3];
    const float* Wo = (const float*)d_in[4];
    float* out = (float*)d_out;

    const size_t NX = (size_t)NB_ * SEQ_ * D_;  // 4194304
    const size_t NW = (size_t)D_ * D_;          // 1048576

    u16* xb  = (u16*)d_ws;
    u16* wqb = xb  + NX;
    u16* wkb = wqb + NW;
    u16* wvb = wkb + NW;
    u16* wob = wvb + NW;
    u16* Qb  = wob + NW;
    u16* Kb  = Qb  + NX;
    u16* Vtb = Kb  + NX;   // V^T: [1024][4096]
    u16* Ab  = Vtb + NX;

    cvt_all<<<dim3(4096), dim3(256), 0, stream>>>(x, Wq, Wk, Wv, Wo,
                                                  xb, wqb, wkb, wvb, wob);

    gemm_qkv<<<dim3(32, 8, 3), dim3(256), 0, stream>>>(xb, wqb, wkb, wvb, Qb, Kb, Vtb);

    // 1024 blocks x 2 independent waves (q-groups 63-px / px), 128-key pairs per iter
    attn_fwd<<<dim3(1024), dim3(128), 0, stream>>>(Qb, Kb, Vtb, Ab);

    gemm_out<<<dim3(32, 8, 1), dim3(256), 0, stream>>>(Ab, wob, out);
}

// Round 15
// 135.516 us; speedup vs baseline: 1.0924x; 1.0924x over previous
//
#include <hip/hip_runtime.h>
#include <hip/hip_bf16.h>

typedef __attribute__((ext_vector_type(8))) short short8;
typedef __attribute__((ext_vector_type(4))) float f32x4;
typedef __attribute__((ext_vector_type(16))) float f32x16;

#define D_   1024
#define SEQ_ 2048
#define NB_  2
#define NH_  16
#define HD_  64
#define LDV_ 4096   // V^T row stride (= B*S)

using u16 = unsigned short;
using u32 = unsigned int;

static __device__ __forceinline__ u16 f2bf(float f) {
    union { __bf16 h; u16 u; } cv;
    cv.h = (__bf16)f;
    return cv.u;
}
static __device__ __forceinline__ float bf2f(u16 u) {
    union { unsigned int i; float f; } v;
    v.i = ((unsigned int)u) << 16;
    return v.f;
}
// pack two f32 -> dword of 2 bf16 (lo = a, hi = b)
static __device__ __forceinline__ u32 pkbf(float a, float b) {
    u32 r;
    asm volatile("v_cvt_pk_bf16_f32 %0, %1, %2" : "=v"(r) : "v"(a), "v"(b));
    return r;
}

// async global->LDS, 16B per lane
static __device__ __forceinline__ void glds16(const u16* g, u16* l) {
    __builtin_amdgcn_global_load_lds(
        (const __attribute__((address_space(1))) unsigned int*)g,
        (__attribute__((address_space(3))) unsigned int*)l, 16, 0, 0);
}

// ---------------- fused f32 -> bf16 convert (one launch for all 5 tensors) ----------------
__global__ __launch_bounds__(256)
void cvt_all(const float* __restrict__ x,  const float* __restrict__ wq,
             const float* __restrict__ wk, const float* __restrict__ wv,
             const float* __restrict__ wo,
             u16* __restrict__ xb,  u16* __restrict__ wqb, u16* __restrict__ wkb,
             u16* __restrict__ wvb, u16* __restrict__ wob)
{
    const int bid = blockIdx.x;
    const float* src; u16* dst; int off;
    if (bid < 2048)      { src = x;  dst = xb;  off = bid; }
    else if (bid < 2560) { src = wq; dst = wqb; off = bid - 2048; }
    else if (bid < 3072) { src = wk; dst = wkb; off = bid - 2560; }
    else if (bid < 3584) { src = wv; dst = wvb; off = bid - 3072; }
    else                 { src = wo; dst = wob; off = bid - 3584; }
    size_t i = ((size_t)off * 256 + threadIdx.x) * 8;
    float4 a = *(const float4*)&src[i];
    float4 b = *(const float4*)&src[i + 4];
    short8 o;
    o[0] = (short)f2bf(a.x); o[1] = (short)f2bf(a.y);
    o[2] = (short)f2bf(a.z); o[3] = (short)f2bf(a.w);
    o[4] = (short)f2bf(b.x); o[5] = (short)f2bf(b.y);
    o[6] = (short)f2bf(b.z); o[7] = (short)f2bf(b.w);
    *(short8*)&dst[i] = o;
}

// ---------------- bf16 GEMM core: Y[m][n] = sum_k A[m][k] * W[n][k] ----------------
// 128x128 tile, BK=32, global_load_lds staging, double-buffered linear LDS (m97 pattern).
template<int OUT_F32>
static __device__ __forceinline__
void gemm_core(const u16* __restrict__ A, const u16* __restrict__ W,
               void* __restrict__ Y, int ldY, int mBase, int nBase,
               u16* lA, u16* lB)
{
    const int t    = threadIdx.x;
    const int lane = t & 63, wid = t >> 6;
    const int wr = wid >> 1, wc = wid & 1;
    const int lr = lane & 15, lg = lane >> 4;

    f32x4 acc[4][4] = {};

    const int srow = t >> 2;         // staging row (+64 for j=1)
    const int scol = (t & 3) * 8;    // staging col (u16)
    const u16* Ag = A + (size_t)(mBase + srow) * D_ + scol;
    const u16* Wg = W + (size_t)(nBase + srow) * D_ + scol;
    const int ldsoff = t * 8;

    auto stage = [&](int buf, int kt) {
#pragma unroll
        for (int j = 0; j < 2; ++j) {
            glds16(Ag + (size_t)j * 64 * D_ + kt * 32, lA + buf * 4096 + j * 2048 + ldsoff);
            glds16(Wg + (size_t)j * 64 * D_ + kt * 32, lB + buf * 4096 + j * 2048 + ldsoff);
        }
    };

    stage(0, 0);
    asm volatile("s_waitcnt vmcnt(0)" ::: "memory");
    __syncthreads();

    int cur = 0;
    for (int kt = 0; kt < 32; ++kt) {
        if (kt < 31) stage(cur ^ 1, kt + 1);
        short8 af[4], bfv[4];
#pragma unroll
        for (int m = 0; m < 4; ++m)
            af[m] = *(const short8*)&lA[cur * 4096 + (wr * 64 + m * 16 + lr) * 32 + lg * 8];
#pragma unroll
        for (int n = 0; n < 4; ++n)
            bfv[n] = *(const short8*)&lB[cur * 4096 + (wc * 64 + n * 16 + lr) * 32 + lg * 8];
        __builtin_amdgcn_s_setprio(1);
#pragma unroll
        for (int m = 0; m < 4; ++m)
#pragma unroll
            for (int n = 0; n < 4; ++n)
                acc[m][n] = __builtin_amdgcn_mfma_f32_16x16x32_bf16(af[m], bfv[n], acc[m][n], 0, 0, 0);
        __builtin_amdgcn_s_setprio(0);
        if (kt < 31) {
            asm volatile("s_waitcnt vmcnt(0)" ::: "memory");
            __syncthreads();
        }
        cur ^= 1;
    }

#pragma unroll
    for (int m = 0; m < 4; ++m)
#pragma unroll
        for (int n = 0; n < 4; ++n)
#pragma unroll
            for (int r = 0; r < 4; ++r) {
                int row = mBase + wr * 64 + m * 16 + lg * 4 + r;
                int col = nBase + wc * 64 + n * 16 + lr;
                if (OUT_F32)
                    ((float*)Y)[(size_t)row * ldY + col] = acc[m][n][r];
                else
                    ((u16*)Y)[(size_t)row * ldY + col] = f2bf(acc[m][n][r]);
            }
}

// fused QKV: z=0 -> Q = x Wq^T, z=1 -> K = x Wk^T, z=2 -> V^T = Wv x^T
__global__ __launch_bounds__(256)
void gemm_qkv(const u16* __restrict__ xb, const u16* __restrict__ wq, const u16* __restrict__ wk,
              const u16* __restrict__ wv, u16* __restrict__ Qo, u16* __restrict__ Ko,
              u16* __restrict__ Vto)
{
    __shared__ u16 lA[2 * 128 * 32];
    __shared__ u16 lB[2 * 128 * 32];
    const int z = blockIdx.z;
    if (z == 0)
        gemm_core<0>(xb, wq, Qo, D_, blockIdx.x * 128, blockIdx.y * 128, lA, lB);
    else if (z == 1)
        gemm_core<0>(xb, wk, Ko, D_, blockIdx.x * 128, blockIdx.y * 128, lA, lB);
    else
        gemm_core<0>(wv, xb, Vto, LDV_, blockIdx.y * 128, blockIdx.x * 128, lA, lB);
}

__global__ __launch_bounds__(256)
void gemm_out(const u16* __restrict__ Ab, const u16* __restrict__ wo, float* __restrict__ out)
{
    __shared__ u16 lA[2 * 128 * 32];
    __shared__ u16 lB[2 * 128 * 32];
    gemm_core<1>(Ab, wo, out, D_, blockIdx.x * 128, blockIdx.y * 128, lA, lB);
}

// ---------------- K/V fragment repack ----------------
// Rewrites K (row-major) and V^T into MFMA-fragment order: 1KB blocks where lane l's
// 16B sit at base + l*16. Pays the uncoalesced gather ONCE; every attention load
// becomes a coalesced 1KB global_load_dwordx4 (16 x 64B transactions vs ~64 x 16B).
// Kpack block (bh, kt32, c): lane l = K[bh][kt32*32 + (l&31)][c*16 + (l>>5)*8 .. +8]
// Vpack block (bh, kv64, t, c): lane l = V^T[h*64 + t*32 + (l&31)][b*S + kv64*64 + c*16 + (l>>5)*8 .. +8]
__global__ __launch_bounds__(256)
void repack_kv(const u16* __restrict__ K, const u16* __restrict__ Vt,
               u16* __restrict__ Kp, u16* __restrict__ Vp)
{
    const int l  = threadIdx.x & 63;
    const int w  = blockIdx.x * 4 + (threadIdx.x >> 6);   // wave id 0..4095
    const int lq = l & 31, hk = l >> 5;
    if (w < 2048) {
        const int bh = w >> 6, kt = w & 63;
        const int b = bh >> 4, h = bh & 15;
        const u16* src = K + (size_t)b * SEQ_ * D_ + (size_t)(kt * 32 + lq) * D_ + h * HD_ + hk * 8;
        u16* dst = Kp + (size_t)(bh * 64 + kt) * 4 * 512 + l * 8;
#pragma unroll
        for (int c = 0; c < 4; ++c)
            *(short8*)(dst + c * 512) = *(const short8*)(src + c * 16);
    } else {
        const int w2 = w - 2048;
        const int bh = w2 >> 6, kv = (w2 >> 1) & 31, t = w2 & 1;
        const int b = bh >> 4, h = bh & 15;
        const u16* src = Vt + (size_t)(h * HD_ + t * 32 + lq) * LDV_ + b * SEQ_ + kv * 64 + hk * 8;
        u16* dst = Vp + (size_t)((bh * 32 + kv) * 2 + t) * 4 * 512 + l * 8;
#pragma unroll
        for (int c = 0; c < 4; ++c)
            *(short8*)(dst + c * 512) = *(const short8*)(src + c * 16);
    }
}

// ---------------- causal flash attention (round-15: r12 core + packed coalesced loads) ----------------
// Proven r12 structure (zero-LDS, zero-barrier, 32x32 swapped-operand in-register softmax,
// cvt_pk+permlane PA build, defer-max), with ALL K/V fragment loads now 1KB coalesced
// reads from Kpack/Vpack (lane offset = l*16). 1024 blocks x 2 waves (q-groups 63-px / px).
__global__ __launch_bounds__(128)
void attn_fwd(const u16* __restrict__ Q, const u16* __restrict__ Kp,
              const u16* __restrict__ Vp, u16* __restrict__ O)
{
    const int l   = threadIdx.x & 63;   // lane within wave
    const int wid = threadIdx.x >> 6;   // 0 or 1
    const int lq = l & 31;              // q-col within tile / hd-col
    const int hk = l >> 5;              // k-half selector (0/1)
    const int id = (int)blockIdx.x;
    const int bh = id & 31;             // id%8 -> XCD-local K/V
    const int px = id >> 5;             // 0..31
    const int b = bh >> 4, h = bh & 15;

    const u16* Qb  = Q  + (size_t)b * SEQ_ * D_ + h * HD_;
    const u16* Kpb = Kp + (size_t)bh * 131072;   // 64 kt32 * 4 c * 512
    const u16* Vpb = Vp + (size_t)bh * 131072;   // 32 kv64 * 2 t * 4 c * 512
    u16*       Ob  = O  + (size_t)b * SEQ_ * D_ + h * HD_;

    const int g     = wid ? px : (63 - px);   // this wave's 32-row q-group
    const int qbase = g * 32;
    const int qrow  = qbase + lq;
    const int ktmax = g >> 1;
    const int loff  = l * 8;                  // u16 offset of this lane's 16B in a block

    // Q fragments (B-operand): qf[c][i] = Q[qrow][16c + 8hk + i], scaled by 0.125*log2(e)
    short8 qf[4];
#pragma unroll
    for (int c = 0; c < 4; ++c) {
        short8 v = *(const short8*)&Qb[(size_t)qrow * D_ + c * 16 + hk * 8];
#pragma unroll
        for (int i = 0; i < 8; ++i)
            v[i] = (short)f2bf(bf2f((u16)v[i]) * 0.18033688011112042f);
        qf[c] = v;
    }

    f32x16 accO[2] = {};        // O[q][hd]: col=hd=32t+lq, row=q=(r&3)+8(r>>2)+4hk
    float m_r = -1e30f, l_r = 0.f;

    // K prefetch tile 0 (kt32 = 0,1): coalesced 1KB loads
    short8 kf[2][4];
#pragma unroll
    for (int t = 0; t < 2; ++t)
#pragma unroll
        for (int c = 0; c < 4; ++c)
            kf[t][c] = *(const short8*)&Kpb[(t * 4 + c) * 512 + loff];

    for (int kt = 0; kt <= ktmax; ++kt) {
        // V fragments for this 64-key tile: coalesced 1KB loads from Vpack
        short8 vf[2][4];
#pragma unroll
        for (int t = 0; t < 2; ++t)
#pragma unroll
            for (int c = 0; c < 4; ++c)
                vf[t][c] = *(const short8*)&Vpb[((kt * 2 + t) * 4 + c) * 512 + loff];

        // S^T = K · Q^T: st[t][r] = S[key = kt*64+32t+(r&3)+8(r>>2)+4hk][q = qrow]
        f32x16 st[2] = {};
        __builtin_amdgcn_s_setprio(1);
#pragma unroll
        for (int t = 0; t < 2; ++t)
#pragma unroll
            for (int c = 0; c < 4; ++c)
                st[t] = __builtin_amdgcn_mfma_f32_32x32x16_bf16(kf[t][c], qf[c], st[t], 0, 0, 0);
        __builtin_amdgcn_s_setprio(0);

        // prefetch next tile's K (kt32 = 2kt+2, 2kt+3): lands during softmax+PV
        if (kt < ktmax) {
#pragma unroll
            for (int t = 0; t < 2; ++t)
#pragma unroll
                for (int c = 0; c < 4; ++c)
                    kf[t][c] = *(const short8*)&Kpb[(((kt + 1) * 2 + t) * 4 + c) * 512 + loff];
        }

        // causal mask (diagonal tile only)
        if (kt == ktmax) {
            const int kb = kt * 64;
#pragma unroll
            for (int t = 0; t < 2; ++t)
#pragma unroll
                for (int r = 0; r < 16; ++r)
                    if (kb + t * 32 + (r & 3) + 8 * (r >> 2) + 4 * hk > qrow)
                        st[t][r] = -1e30f;
        }

        // in-register online softmax (exp2 domain); partner lane^32 holds the other keys
        float m0 = fmaxf(st[0][0], st[0][1]), m1 = fmaxf(st[0][2], st[0][3]);
        float m2 = fmaxf(st[0][4], st[0][5]), m3 = fmaxf(st[0][6], st[0][7]);
#pragma unroll
        for (int r = 8; r < 16; r += 4) {
            m0 = fmaxf(m0, fmaxf(st[0][r], st[0][r + 1]));
            m1 = fmaxf(m1, fmaxf(st[0][r + 2], st[0][r + 3]));
        }
#pragma unroll
        for (int r = 0; r < 16; r += 4) {
            m2 = fmaxf(m2, fmaxf(st[1][r], st[1][r + 1]));
            m3 = fmaxf(m3, fmaxf(st[1][r + 2], st[1][r + 3]));
        }
        float pmax = fmaxf(fmaxf(m0, m1), fmaxf(m2, m3));
        pmax = fmaxf(pmax, __shfl_xor(pmax, 32));
        // defer-max (T13, THR=8)
        if (!__all(pmax <= m_r + 8.f)) {
            const float mn = fmaxf(m_r, pmax);
            const float al = exp2f(m_r - mn);
            m_r = mn;
            l_r *= al;
#pragma unroll
            for (int t = 0; t < 2; ++t)
#pragma unroll
                for (int r = 0; r < 16; ++r) accO[t][r] *= al;
        }
        float rs0 = 0.f, rs1 = 0.f;
#pragma unroll
        for (int t = 0; t < 2; ++t)
#pragma unroll
            for (int r = 0; r < 16; r += 2) {
                float p0 = exp2f(st[t][r]     - m_r);
                float p1 = exp2f(st[t][r + 1] - m_r);
                st[t][r] = p0; st[t][r + 1] = p1;
                rs0 += p0; rs1 += p1;
            }
        float rsum = rs0 + rs1;
        rsum += __shfl_xor(rsum, 32);
        l_r += rsum;

        // PA build (T12): per 16-key chunk c, 4 cvt_pk + 2 permlane32_swap -> A-frag
        short8 pa[4];
#pragma unroll
        for (int c = 0; c < 4; ++c) {
            const int tt = c >> 1, base = (c & 1) * 8;
            u32 a0 = pkbf(st[tt][base + 0], st[tt][base + 1]);
            u32 b0 = pkbf(st[tt][base + 4], st[tt][base + 5]);
            u32 a1 = pkbf(st[tt][base + 2], st[tt][base + 3]);
            u32 b1 = pkbf(st[tt][base + 6], st[tt][base + 7]);
            asm volatile("v_permlane32_swap_b32 %0, %1" : "+v"(a0), "+v"(b0));
            asm volatile("v_permlane32_swap_b32 %0, %1" : "+v"(a1), "+v"(b1));
            union { u32 w[4]; short8 s; } u;
            u.w[0] = a0; u.w[1] = a1; u.w[2] = b0; u.w[3] = b1;
            pa[c] = u.s;
        }

        // O += P · V : accO[t] over hd-tile t
        __builtin_amdgcn_s_setprio(1);
#pragma unroll
        for (int t = 0; t < 2; ++t)
#pragma unroll
            for (int c = 0; c < 4; ++c)
                accO[t] = __builtin_amdgcn_mfma_f32_32x32x16_bf16(pa[c], vf[t][c], accO[t], 0, 0, 0);
        __builtin_amdgcn_s_setprio(0);
    }

    // epilogue: O[q][hd] = accO / l; l_r lives at lane (q&31) -> gather via shfl
    const float inv = 1.f / l_r;
#pragma unroll
    for (int r = 0; r < 16; ++r) {
        const int qe = (r & 3) + 8 * (r >> 2) + 4 * hk;   // 0..31
        const float li = __shfl(inv, qe);
        const size_t qoff = (size_t)(qbase + qe) * D_;
#pragma unroll
        for (int t = 0; t < 2; ++t)
            Ob[qoff + t * 32 + lq] = f2bf(accO[t][r] * li);
    }
}

extern "C" void kernel_launch(void* const* d_in, const int* in_sizes, int n_in,
                              void* d_out, int out_size, void* d_ws, size_t ws_size,
                              hipStream_t stream)
{
    const float* x  = (const float*)d_in[0];
    const float* Wq = (const float*)d_in[1];
    const float* Wk = (const float*)d_in[2];
    const float* Wv = (const float*)d_in[3];
    const float* Wo = (const float*)d_in[4];
    float* out = (float*)d_out;

    const size_t NX = (size_t)NB_ * SEQ_ * D_;  // 4194304
    const size_t NW = (size_t)D_ * D_;          // 1048576

    // ws layout (48 MB of bf16) with staged reuse:
    //   xb   : x bf16 for gemm_qkv       -> reused as Kpack after gemm_qkv
    //   Ab   : (initially free)          -> Vpack
    //   Kb   : row-major K (repack src)  -> reused as attention OUTPUT after repack
    u16* xb  = (u16*)d_ws;
    u16* wqb = xb  + NX;
    u16* wkb = wqb + NW;
    u16* wvb = wkb + NW;
    u16* wob = wvb + NW;
    u16* Qb  = wob + NW;
    u16* Kb  = Qb  + NX;
    u16* Vtb = Kb  + NX;   // V^T: [1024][4096]
    u16* Ab  = Vtb + NX;

    u16* Kpk = xb;         // 32*64*4*512 = 4194304 u16 (exact fit)
    u16* Vpk = Ab;         // 32*32*2*4*512 = 4194304 u16 (exact fit)
    u16* Aout = Kb;        // attention output (K dead after repack)

    cvt_all<<<dim3(4096), dim3(256), 0, stream>>>(x, Wq, Wk, Wv, Wo,
                                                  xb, wqb, wkb, wvb, wob);

    gemm_qkv<<<dim3(32, 8, 3), dim3(256), 0, stream>>>(xb, wqb, wkb, wvb, Qb, Kb, Vtb);

    // fragment repack: K, V^T -> coalesced-consumable Kpack/Vpack
    repack_kv<<<dim3(1024), dim3(256), 0, stream>>>(Kb, Vtb, Kpk, Vpk);

    // 1024 blocks x 2 independent waves (q-groups 63-px / px), packed loads
    attn_fwd<<<dim3(1024), dim3(128), 0, stream>>>(Qb, Kpk, Vpk, Aout);

    gemm_out<<<dim3(32, 8, 1), dim3(256), 0, stream>>>(Aout, wob, out);
}